// Round 9
// baseline (2602.506 us; speedup 1.0000x reference)
//
#include <hip/hip_runtime.h>

// SimpleRNN: B=64,T=512,I=128,H=1024,L=4,O=128
// Round 6 (7th resubmit; seven GPU-acquisition timeouts, kernel never ran):
// round-5 skeleton + latency-hiding of the synchronization loop:
//  - early own-group snapshot (issued at publish, checked end of precompute)
//  - speculative h pre-gather overlapped with a3 MFMAs (acquire-safe)
//  - seq gather pre-issued at epilogue, overlapping the release store-drain
//  - 4 independent MFMA accumulation chains
#define B_ 64
#define T_ 512
#define I_ 128
#define H_ 1024
#define L_ 4
#define O_ 128
#define M_ (B_ * T_)
#define D_ 32  // inter-layer seq ring depth (steps)

typedef __attribute__((ext_vector_type(8))) short bf16x8_t;
typedef __attribute__((ext_vector_type(4))) float f32x4_t;

__device__ __forceinline__ unsigned short f2bf(float x) {
  unsigned int u = __builtin_bit_cast(unsigned int, x);
  u += 0x7FFFu + ((u >> 16) & 1u);
  return (unsigned short)(u >> 16);
}
__device__ __forceinline__ float bf2f(unsigned short h) {
  return __builtin_bit_cast(float, ((unsigned int)h) << 16);
}
__device__ __forceinline__ f32x4_t mfma16(bf16x8_t a, bf16x8_t b, f32x4_t c) {
  return __builtin_amdgcn_mfma_f32_16x16x32_bf16(a, b, c, 0, 0, 0);
}

// Relaxed agent-scope atomics (served at device coherence point; proven r2).
__device__ __forceinline__ unsigned aldc(const unsigned* p) {
  return __hip_atomic_load(p, __ATOMIC_RELAXED, __HIP_MEMORY_SCOPE_AGENT);
}
__device__ __forceinline__ unsigned long long ald64(const unsigned long long* p) {
  return __hip_atomic_load(p, __ATOMIC_RELAXED, __HIP_MEMORY_SCOPE_AGENT);
}
__device__ __forceinline__ void ast32(unsigned* p, unsigned v) {
  __hip_atomic_store(p, v, __ATOMIC_RELAXED, __HIP_MEMORY_SCOPE_AGENT);
}

// All threads poll 16 member counters (stride 32 u32 = 128B lines) until all
// >= target; returns wave-uniform min (lanes 16.. mirror members 0-15).
__device__ __forceinline__ unsigned wait_ge(const unsigned* base, unsigned target) {
  const int i = threadIdx.x & 15;
  unsigned v;
  while (true) {
    v = aldc(base + i * 32);
    if (__ballot(v < target) == 0ull) break;
    __builtin_amdgcn_s_sleep(2);
  }
  unsigned mn = v;
  mn = min(mn, (unsigned)__shfl_xor((int)mn, 1));
  mn = min(mn, (unsigned)__shfl_xor((int)mn, 2));
  mn = min(mn, (unsigned)__shfl_xor((int)mn, 4));
  mn = min(mn, (unsigned)__shfl_xor((int)mn, 8));
  mn = min(mn, (unsigned)__shfl_xor((int)mn, 16));
  mn = min(mn, (unsigned)__shfl_xor((int)mn, 32));
  return mn;
}

// Own-group barrier poll: no min-reduce needed.
__device__ __forceinline__ void wait_all(const unsigned* base, unsigned target) {
  const int i = threadIdx.x & 15;
  while (true) {
    unsigned v = aldc(base + i * 32);
    if (__ballot(v < target) == 0ull) break;
    __builtin_amdgcn_s_sleep(2);
  }
}

// ---------------------------------------------------------------------------
// MFMA GEMM (round-1, proven) — used only for the final FC here.
// ---------------------------------------------------------------------------
template <int K, int N, bool ASPLIT, bool OUTBF16>
__global__ __launch_bounds__(256, 2) void gemm_k(
    const void* __restrict__ Aq, const float* __restrict__ Wf,
    const float* __restrict__ bias1, const float* __restrict__ bias2,
    void* __restrict__ Cq) {
  extern __shared__ unsigned short smem[];
  unsigned short* Ahi = smem;
  unsigned short* Alo = Ahi + (ASPLIT ? 8192 : 0);
  unsigned short* Bhi = Alo + 8192;
  unsigned short* Blo = Bhi + 8192;

  const int tid = threadIdx.x;
  const int wave = tid >> 6, lane = tid & 63;
  const int wm = wave >> 1, wn = wave & 1;
  const int lm = lane & 15, lk = lane >> 4;
  const int m0 = blockIdx.y * 128, n0 = blockIdx.x * 128;

  f32x4_t acc[4][4] = {};

  for (int kc = 0; kc < K; kc += 64) {
    __syncthreads();
#pragma unroll
    for (int p = 0; p < 4; ++p) {
      int fl = p * 256 + tid;
      int row = fl & 127, ko = (fl >> 7) & 3, kit = fl >> 9;
      int kk = kc + kit * 32 + ko * 8;
      if (ASPLIT) {
        const float* src = (const float*)Aq + (size_t)(m0 + row) * K + kk;
        union { bf16x8_t s; unsigned short u[8]; } th, tl;
#pragma unroll
        for (int e = 0; e < 8; ++e) {
          float v = src[e];
          unsigned short h = f2bf(v);
          th.u[e] = (short)h;
          tl.u[e] = (short)f2bf(v - bf2f(h));
        }
        *(bf16x8_t*)(Ahi + (size_t)fl * 8) = th.s;
        *(bf16x8_t*)(Alo + (size_t)fl * 8) = tl.s;
      } else {
        const unsigned short* src = (const unsigned short*)Aq + (size_t)(m0 + row) * K + kk;
        *(bf16x8_t*)(Ahi + (size_t)fl * 8) = *(const bf16x8_t*)src;
      }
    }
#pragma unroll
    for (int p = 0; p < 4; ++p) {
      int fl = p * 256 + tid;
      int row = fl & 127, ko = (fl >> 7) & 3, kit = fl >> 9;
      int kk = kc + kit * 32 + ko * 8;
      const float* src = Wf + (size_t)(n0 + row) * K + kk;
      union { bf16x8_t s; unsigned short u[8]; } th, tl;
#pragma unroll
      for (int e = 0; e < 8; ++e) {
        float v = src[e];
        unsigned short h = f2bf(v);
        th.u[e] = (short)h;
        tl.u[e] = (short)f2bf(v - bf2f(h));
      }
      *(bf16x8_t*)(Bhi + (size_t)fl * 8) = th.s;
      *(bf16x8_t*)(Blo + (size_t)fl * 8) = tl.s;
    }
    __syncthreads();
#pragma unroll
    for (int kit = 0; kit < 2; ++kit) {
      bf16x8_t bhf[4], blf[4];
#pragma unroll
      for (int n = 0; n < 4; ++n) {
        int br = wn * 64 + n * 16 + lm;
        bhf[n] = *(const bf16x8_t*)(Bhi + ((size_t)(kit * 4 + lk) * 128 + br) * 8);
        blf[n] = *(const bf16x8_t*)(Blo + ((size_t)(kit * 4 + lk) * 128 + br) * 8);
      }
#pragma unroll
      for (int m = 0; m < 4; ++m) {
        int ar = wm * 64 + m * 16 + lm;
        bf16x8_t a = *(const bf16x8_t*)(Ahi + ((size_t)(kit * 4 + lk) * 128 + ar) * 8);
        bf16x8_t al;
        if (ASPLIT) al = *(const bf16x8_t*)(Alo + ((size_t)(kit * 4 + lk) * 128 + ar) * 8);
#pragma unroll
        for (int n = 0; n < 4; ++n) {
          acc[m][n] = mfma16(a, bhf[n], acc[m][n]);
          acc[m][n] = mfma16(a, blf[n], acc[m][n]);
          if (ASPLIT) acc[m][n] = mfma16(al, bhf[n], acc[m][n]);
        }
      }
    }
  }
#pragma unroll
  for (int n = 0; n < 4; ++n) {
    int col = n0 + wn * 64 + n * 16 + lm;
    float bv = bias1[col];
    if (bias2 != nullptr) bv += bias2[col];
#pragma unroll
    for (int m = 0; m < 4; ++m) {
#pragma unroll
      for (int r = 0; r < 4; ++r) {
        int row = m0 + wm * 64 + m * 16 + lk * 4 + r;
        float v = acc[m][n][r] + bv;
        if (OUTBF16)
          ((unsigned short*)Cq)[(size_t)row * N + col] = f2bf(v);
        else
          ((float*)Cq)[(size_t)row * N + col] = v;
      }
    }
  }
}

// x pre-split: fp32 -> (hi, lo) bf16 planes.
__global__ __launch_bounds__(256) void splitx_k(const float* __restrict__ x,
                                               unsigned short* __restrict__ xhi,
                                               unsigned short* __restrict__ xlo) {
  int i = (blockIdx.x * 256 + threadIdx.x) * 4;
  float4 v = *(const float4*)(x + i);
  ushort4 h, lo;
  h.x = f2bf(v.x); lo.x = f2bf(v.x - bf2f(h.x));
  h.y = f2bf(v.y); lo.y = f2bf(v.y - bf2f(h.y));
  h.z = f2bf(v.z); lo.z = f2bf(v.z - bf2f(h.z));
  h.w = f2bf(v.w); lo.w = f2bf(v.w - bf2f(h.w));
  *(ushort4*)(xhi + i) = h;
  *(ushort4*)(xlo + i) = lo;
}

// ---------------------------------------------------------------------------
// Persistent pipelined RNN. 256 blocks: l = bid>>6, me = (bid&63)>>2,
// bg = bid&3; 64 neurons x 16 batches per block; group (l,bg) = 16 members.
// Round-6 per-step schedule (fast path):
//   [htmp pre-gathered last iter] stage h | sync | a0 MFMA | dn-wait |
//   epilogue stores | pre-issue seq gather | sync (drains stores+gather) |
//   publish t+2 | issue own snapshot | deferred s3 | stage seq | sync |
//   check snapshot -> pre-gather h(t+1) | a3 MFMA (hides h gather)
// Slow paths fall back to blocking polls (round-5 behavior). Wait conditions
// are unchanged; only observation points moved (monotone counters => safe).
// ---------------------------------------------------------------------------
__global__ __launch_bounds__(256, 1) void rnn_k(
    const float* __restrict__ hidden,
    const float* __restrict__ Wih0, const float* __restrict__ Whh0,
    const float* __restrict__ bih0, const float* __restrict__ bhh0,
    const float* __restrict__ WihL, const float* __restrict__ WhhL,
    const float* __restrict__ bihL, const float* __restrict__ bhhL,
    const unsigned short* __restrict__ xhi, const unsigned short* __restrict__ xlo,
    unsigned short* __restrict__ ring, unsigned short* __restrict__ seqr,
    unsigned short* __restrict__ s3, float* __restrict__ hn,
    unsigned* __restrict__ prog) {
  extern __shared__ char lds[];  // 64 KB: h 32K | seq 32K
  char* ldsH = lds;
  char* ldsS = lds + 32768;
  const int tid = threadIdx.x;
  const int wave = tid >> 6, lane = tid & 63;
  const int lm = lane & 15, lk = lane >> 4;
  const int bid = blockIdx.x;
  const int l = bid >> 6;
  const int sub = bid & 63;
  const int me = sub >> 2, bg = sub & 3;
  const int g = l * 4 + bg;
  const int j0 = me * 64 + wave * 16;
  const int j = j0 + lm;

  // ---- weight fragments (bf16-hi) in registers
  const float* Whh = (l == 0) ? Whh0 : WhhL + (size_t)(l - 1) * H_ * H_;
  bf16x8_t bh[32];
#pragma unroll
  for (int kit = 0; kit < 32; ++kit) {
    const float* src = Whh + (size_t)j * H_ + kit * 32 + lk * 8;
    union { bf16x8_t s; unsigned short u[8]; } th;
#pragma unroll
    for (int e = 0; e < 8; ++e) th.u[e] = (short)f2bf(src[e]);
    bh[kit] = th.s;
  }
  bf16x8_t bw[32];
  bf16x8_t w0h[4], w0l[4];
  if (l > 0) {
    const float* Wih = WihL + (size_t)(l - 1) * H_ * H_;
#pragma unroll
    for (int kit = 0; kit < 32; ++kit) {
      const float* src = Wih + (size_t)j * H_ + kit * 32 + lk * 8;
      union { bf16x8_t s; unsigned short u[8]; } th;
#pragma unroll
      for (int e = 0; e < 8; ++e) th.u[e] = (short)f2bf(src[e]);
      bw[kit] = th.s;
    }
  } else {
#pragma unroll
    for (int kit = 0; kit < 4; ++kit) {
      const float* src = Wih0 + (size_t)j * I_ + kit * 32 + lk * 8;
      union { bf16x8_t s; unsigned short u[8]; } th, tl;
#pragma unroll
      for (int e = 0; e < 8; ++e) {
        float v = src[e];
        unsigned short h = f2bf(v);
        th.u[e] = (short)h;
        tl.u[e] = (short)f2bf(v - bf2f(h));
      }
      w0h[kit] = th.s; w0l[kit] = tl.s;
    }
  }
  float bias = (l == 0) ? (bih0[j] + bhh0[j])
                        : (bihL[(size_t)(l - 1) * H_ + j] + bhhL[(size_t)(l - 1) * H_ + j]);

  // ---- init: h0 -> ring slot 1 (this block's 64-neuron portion, u32-packed)
  {
    unsigned* r1 = (unsigned*)(ring + ((size_t)(l * 2 + 1) * 4 + bg) * 16384);
#pragma unroll
    for (int q = 0; q < 2; ++q) {
      int s = q * 256 + tid;  // [0,512) -> u32 idx me*512 + s
      int J = s >> 6, b16 = (s >> 2) & 15, h4 = s & 3;
      int jj = me * 64 + J * 8 + h4 * 2;
      const float* hp = hidden + (size_t)l * B_ * H_ + (bg * 16 + b16) * H_ + jj;
      unsigned p0 = f2bf(hp[0]), p1 = f2bf(hp[1]);
      ast32(r1 + me * 512 + s, p0 | (p1 << 16));
    }
  }
  __syncthreads();  // drains vmcnt for the whole block
  if (tid == 0) ast32(prog + (size_t)(g * 16 + me) * 32, 1u);

  const unsigned* ownB = prog + (size_t)g * 512;
  const unsigned* upB = prog + (size_t)((l - 1) * 4 + bg) * 512;  // l>0 only
  const unsigned* dnB = prog + (size_t)((l + 1) * 4 + bg) * 512;  // l<3 only
  unsigned upMin = 1, dnMin = 1;
  f32x4_t a3s = {0.f, 0.f, 0.f, 0.f};
  unsigned long long htmp[16];
  unsigned long long stmp[16];
  bf16x8_t xh4[4], xl4[4];
  bool hPre = false, sPre = false;
  unsigned snap = 0;

  auto gatherH = [&](int tt) {
    const unsigned long long* hp = (const unsigned long long*)(ring +
        ((size_t)(l * 2 + ((tt & 1) ^ 1)) * 4 + bg) * 16384);
#pragma unroll
    for (int i = 0; i < 16; ++i) htmp[i] = ald64(hp + i * 256 + tid);
  };
  auto gatherSeq = [&](int tt) {
    const unsigned long long* sp = (const unsigned long long*)(seqr +
        ((size_t)((l - 1) * D_ + (tt & (D_ - 1))) * 4 + bg) * 16384);
#pragma unroll
    for (int i = 0; i < 16; ++i) stmp[i] = ald64(sp + i * 256 + tid);
  };
  auto gatherX = [&](int tt) {
    const int b = bg * 16 + lm;
#pragma unroll
    for (int kit = 0; kit < 4; ++kit) {
      const size_t xo = ((size_t)b * T_ + tt) * I_ + kit * 32 + lk * 8;
      xh4[kit] = *(const bf16x8_t*)(xhi + xo);
      xl4[kit] = *(const bf16x8_t*)(xlo + xo);
    }
  };

  // Finish the input-projection precompute for step tt (fills a3s); also
  // checks the early own-group snapshot and, on success, pre-gathers h(tt)
  // so its L3 latency hides under the a3 MFMAs.
  auto finishPre = [&](int tt) {
    if (l > 0) {
      if (!sPre) {
        if (upMin < (unsigned)(tt + 2)) upMin = wait_ge(upB, (unsigned)(tt + 2));
        asm volatile("" ::: "memory");
        gatherSeq(tt);
      }
      unsigned long long* dsp = (unsigned long long*)ldsS;
#pragma unroll
      for (int i = 0; i < 16; ++i) dsp[i * 256 + tid] = stmp[i];
      __syncthreads();
    }
    // own-group snapshot check: need all peers >= tt+1 (monotone -> safe)
    hPre = (__ballot(snap < (unsigned)(tt + 1)) == 0ull);
    asm volatile("" ::: "memory");
    if (hPre) gatherH(tt);
    if (l > 0) {
      f32x4_t x0 = {0.f,0.f,0.f,0.f}, x1 = {0.f,0.f,0.f,0.f};
      f32x4_t x2 = {0.f,0.f,0.f,0.f}, x3 = {0.f,0.f,0.f,0.f};
#pragma unroll
      for (int kit = 0; kit < 32; ++kit) {
        const int fo = ((kit * 4 + lk) * 16 + lm) * 16;
        bf16x8_t as = *(const bf16x8_t*)(ldsS + fo);
        if ((kit & 3) == 0)      x0 = mfma16(as, bw[kit], x0);
        else if ((kit & 3) == 1) x1 = mfma16(as, bw[kit], x1);
        else if ((kit & 3) == 2) x2 = mfma16(as, bw[kit], x2);
        else                     x3 = mfma16(as, bw[kit], x3);
      }
      a3s = (x0 + x1) + (x2 + x3);
    } else {
      f32x4_t x0 = {0.f,0.f,0.f,0.f}, x1 = {0.f,0.f,0.f,0.f}, x2 = {0.f,0.f,0.f,0.f};
#pragma unroll
      for (int kit = 0; kit < 4; ++kit) {
        x0 = mfma16(xh4[kit], w0h[kit], x0);
        x1 = mfma16(xl4[kit], w0h[kit], x1);
        x2 = mfma16(xh4[kit], w0l[kit], x2);
      }
      a3s = (x0 + x1) + x2;
    }
  };

  // ---- prologue: mirror of loop tail for t = 0
  snap = aldc(ownB + (tid & 15) * 32);
  sPre = false;
  if (l == 0) { gatherX(0); sPre = true; }
  finishPre(0);

  for (int t = 0; t < T_; ++t) {
    // A. own-group barrier slow path (snapshot missed) + h gather
    if (!hPre) {
      wait_all(ownB, (unsigned)(t + 1));
      asm volatile("" ::: "memory");
      gatherH(t);
    }
    // B. stage h -> LDS (frag order preserved)
    {
      unsigned long long* dh = (unsigned long long*)ldsH;
#pragma unroll
      for (int i = 0; i < 16; ++i) dh[i * 256 + tid] = htmp[i];
    }
    __syncthreads();
    // C. a0 = h @ Whh^T (4 independent accumulation chains)
    f32x4_t h0 = {0.f,0.f,0.f,0.f}, h1 = {0.f,0.f,0.f,0.f};
    f32x4_t h2 = {0.f,0.f,0.f,0.f}, h3 = {0.f,0.f,0.f,0.f};
#pragma unroll
    for (int kit = 0; kit < 32; ++kit) {
      const int fo = ((kit * 4 + lk) * 16 + lm) * 16;
      bf16x8_t ah = *(const bf16x8_t*)(ldsH + fo);
      if ((kit & 3) == 0)      h0 = mfma16(ah, bh[kit], h0);
      else if ((kit & 3) == 1) h1 = mfma16(ah, bh[kit], h1);
      else if ((kit & 3) == 2) h2 = mfma16(ah, bh[kit], h2);
      else                     h3 = mfma16(ah, bh[kit], h3);
    }
    f32x4_t a0 = (h0 + h1) + (h2 + h3);
    // D. downstream back-pressure before overwriting seq slot (cached)
    if (l < 3 && t >= D_ && dnMin < (unsigned)(t - D_ + 2))
      dnMin = wait_ge(dnB, (unsigned)(t - D_ + 2));
    // E. epilogue: lane holds (j, b = bg*16 + lk*4 + r); u32 pair-packed stores
    unsigned* rwu = (unsigned*)(ring + ((size_t)(l * 2 + (t & 1)) * 4 + bg) * 16384);
    unsigned* swu = (unsigned*)(seqr + ((size_t)(l * D_ + (t & (D_ - 1))) * 4 + bg) * 16384);
    unsigned hi4[4];
#pragma unroll
    for (int r = 0; r < 4; ++r) {
      const int b15 = lk * 4 + r;
      float v = a0[r] + a3s[r] + bias;
      v = fmaxf(v, 0.f);
      unsigned hi = f2bf(v);
      hi4[r] = hi;
      unsigned other = (unsigned)__shfl_xor((int)hi, 1);
      if (!(lm & 1)) {
        const unsigned pk = hi | (other << 16);
        const int p32 = ((j >> 3) * 16 + b15) * 4 + ((j & 7) >> 1);
        ast32(rwu + p32, pk);
        if (l < 3) ast32(swu + p32, pk);
      }
      if (t == T_ - 1) hn[(size_t)l * B_ * H_ + (bg * 16 + b15) * H_ + j] = v;
    }
    // E2. pre-issue next-step seq/x gather: overlaps the release store-drain
    sPre = false;
    if (t + 1 < T_) {
      if (l > 0) {
        if (upMin >= (unsigned)(t + 3)) { gatherSeq(t + 1); sPre = true; }
      } else {
        gatherX(t + 1); sPre = true;
      }
    }
    // F. release: __syncthreads drains all waves' stores (and pre-gathers),
    // then publish progress.
    __syncthreads();
    if (tid == 0) ast32(prog + (size_t)(g * 16 + me) * 32, (unsigned)(t + 2));
    // G. early snapshot of own-group counters for next iteration's barrier
    snap = aldc(ownB + (tid & 15) * 32);
    // H. deferred scatter stores (not needed by peers; off the publish path)
    if (l == 3) {
#pragma unroll
      for (int r = 0; r < 4; ++r)
        s3[((size_t)(bg * 16 + lk * 4 + r) * T_ + t) * H_ + j] = (unsigned short)hi4[r];
    }
    // I. finish precompute for t+1 (hides snapshot latency + h pre-gather)
    if (t + 1 < T_) finishPre(t + 1);
  }
}

// ---------------------------------------------------------------------------
// ws layout: prog 32KB (16 groups x 16 members x 128B) | pad to 64K |
// ring 1MB (u16 [l][slot2][bg][16384]) | seqr 12MB | s3 64MB | xhi 8MB |
// xlo 8MB  => ~93 MB.
// ---------------------------------------------------------------------------
extern "C" void kernel_launch(void* const* d_in, const int* in_sizes, int n_in,
                              void* d_out, int out_size, void* d_ws, size_t ws_size,
                              hipStream_t stream) {
  const float* x = (const float*)d_in[0];
  const float* hidden = (const float*)d_in[1];
  const float* Wih0 = (const float*)d_in[2];
  const float* Whh0 = (const float*)d_in[3];
  const float* bih0 = (const float*)d_in[4];
  const float* bhh0 = (const float*)d_in[5];
  const float* WihL = (const float*)d_in[6];
  const float* WhhL = (const float*)d_in[7];
  const float* bihL = (const float*)d_in[8];
  const float* bhhL = (const float*)d_in[9];
  const float* Wfc = (const float*)d_in[10];
  const float* bfc = (const float*)d_in[11];
  float* out = (float*)d_out;
  float* hn = out + (size_t)M_ * O_;

  char* ws = (char*)d_ws;
  unsigned* prog = (unsigned*)ws;
  unsigned short* ring = (unsigned short*)(ws + 65536);
  unsigned short* seqr = (unsigned short*)(ws + 65536 + (1u << 20));
  unsigned short* s3 = (unsigned short*)(ws + 65536 + (1u << 20) + (12u << 20));
  unsigned short* xhi = (unsigned short*)(ws + 65536 + (1u << 20) + (12u << 20) + (64u << 20));
  unsigned short* xlo = xhi + (size_t)B_ * T_ * I_;

  hipMemsetAsync(ws, 0, 65536, stream);  // progress counters
  splitx_k<<<(B_ * T_ * I_) / 1024, 256, 0, stream>>>(x, xhi, xlo);

  hipFuncSetAttribute((const void*)rnn_k, hipFuncAttributeMaxDynamicSharedMemorySize,
                      64 * 1024);
  rnn_k<<<256, 256, 64 * 1024, stream>>>(hidden, Wih0, Whh0, bih0, bhh0,
                                         WihL, WhhL, bihL, bhhL, xhi, xlo,
                                         ring, seqr, s3, hn, prog);

  gemm_k<H_, O_, false, false><<<dim3(O_ / 128, M_ / 128), 256, 48 * 1024, stream>>>(
      (const void*)s3, Wfc, bfc, nullptr, (void*)out);
}

// Round 11
// 2428.498 us; speedup vs baseline: 1.0717x; 1.0717x over previous
//
#include <hip/hip_runtime.h>

// SimpleRNN: B=64,T=512,I=128,H=1024,L=4,O=128
// Round 7 (resubmit; GPU-acquisition timeout, kernel never ran).
// Fixes R6's regression (2526us vs R5 1872us). R6 placed the own-group
// snapshot ballot BEFORE the a3 MFMAs, putting a serial ~700cy L3 wait on
// every step's critical path. R7 moves the check AFTER the a3 accumulation:
// snapshot load (issued at publish) completes under the
// seq-gather+stage+sync+MFMA window (~1100cy for l>0), so the ballot is free;
// on hit, gatherH replaces the loop-top poll (+gather), saving ~700cy/step.
#define B_ 64
#define T_ 512
#define I_ 128
#define H_ 1024
#define L_ 4
#define O_ 128
#define M_ (B_ * T_)
#define D_ 32  // inter-layer seq ring depth (steps)

typedef __attribute__((ext_vector_type(8))) short bf16x8_t;
typedef __attribute__((ext_vector_type(4))) float f32x4_t;

__device__ __forceinline__ unsigned short f2bf(float x) {
  unsigned int u = __builtin_bit_cast(unsigned int, x);
  u += 0x7FFFu + ((u >> 16) & 1u);
  return (unsigned short)(u >> 16);
}
__device__ __forceinline__ float bf2f(unsigned short h) {
  return __builtin_bit_cast(float, ((unsigned int)h) << 16);
}
__device__ __forceinline__ f32x4_t mfma16(bf16x8_t a, bf16x8_t b, f32x4_t c) {
  return __builtin_amdgcn_mfma_f32_16x16x32_bf16(a, b, c, 0, 0, 0);
}

// Relaxed agent-scope atomics (served at device coherence point; proven r2).
__device__ __forceinline__ unsigned aldc(const unsigned* p) {
  return __hip_atomic_load(p, __ATOMIC_RELAXED, __HIP_MEMORY_SCOPE_AGENT);
}
__device__ __forceinline__ unsigned long long ald64(const unsigned long long* p) {
  return __hip_atomic_load(p, __ATOMIC_RELAXED, __HIP_MEMORY_SCOPE_AGENT);
}
__device__ __forceinline__ void ast32(unsigned* p, unsigned v) {
  __hip_atomic_store(p, v, __ATOMIC_RELAXED, __HIP_MEMORY_SCOPE_AGENT);
}

// All threads poll 16 member counters (stride 32 u32 = 128B lines) until all
// >= target; returns wave-uniform min (lanes 16.. mirror members 0-15).
__device__ __forceinline__ unsigned wait_ge(const unsigned* base, unsigned target) {
  const int i = threadIdx.x & 15;
  unsigned v;
  while (true) {
    v = aldc(base + i * 32);
    if (__ballot(v < target) == 0ull) break;
    __builtin_amdgcn_s_sleep(2);
  }
  unsigned mn = v;
  mn = min(mn, (unsigned)__shfl_xor((int)mn, 1));
  mn = min(mn, (unsigned)__shfl_xor((int)mn, 2));
  mn = min(mn, (unsigned)__shfl_xor((int)mn, 4));
  mn = min(mn, (unsigned)__shfl_xor((int)mn, 8));
  mn = min(mn, (unsigned)__shfl_xor((int)mn, 16));
  mn = min(mn, (unsigned)__shfl_xor((int)mn, 32));
  return mn;
}

// Own-group barrier poll: no min-reduce needed.
__device__ __forceinline__ void wait_all(const unsigned* base, unsigned target) {
  const int i = threadIdx.x & 15;
  while (true) {
    unsigned v = aldc(base + i * 32);
    if (__ballot(v < target) == 0ull) break;
    __builtin_amdgcn_s_sleep(2);
  }
}

// ---------------------------------------------------------------------------
// MFMA GEMM (round-1, proven) — used only for the final FC here.
// ---------------------------------------------------------------------------
template <int K, int N, bool ASPLIT, bool OUTBF16>
__global__ __launch_bounds__(256, 2) void gemm_k(
    const void* __restrict__ Aq, const float* __restrict__ Wf,
    const float* __restrict__ bias1, const float* __restrict__ bias2,
    void* __restrict__ Cq) {
  extern __shared__ unsigned short smem[];
  unsigned short* Ahi = smem;
  unsigned short* Alo = Ahi + (ASPLIT ? 8192 : 0);
  unsigned short* Bhi = Alo + 8192;
  unsigned short* Blo = Bhi + 8192;

  const int tid = threadIdx.x;
  const int wave = tid >> 6, lane = tid & 63;
  const int wm = wave >> 1, wn = wave & 1;
  const int lm = lane & 15, lk = lane >> 4;
  const int m0 = blockIdx.y * 128, n0 = blockIdx.x * 128;

  f32x4_t acc[4][4] = {};

  for (int kc = 0; kc < K; kc += 64) {
    __syncthreads();
#pragma unroll
    for (int p = 0; p < 4; ++p) {
      int fl = p * 256 + tid;
      int row = fl & 127, ko = (fl >> 7) & 3, kit = fl >> 9;
      int kk = kc + kit * 32 + ko * 8;
      if (ASPLIT) {
        const float* src = (const float*)Aq + (size_t)(m0 + row) * K + kk;
        union { bf16x8_t s; unsigned short u[8]; } th, tl;
#pragma unroll
        for (int e = 0; e < 8; ++e) {
          float v = src[e];
          unsigned short h = f2bf(v);
          th.u[e] = (short)h;
          tl.u[e] = (short)f2bf(v - bf2f(h));
        }
        *(bf16x8_t*)(Ahi + (size_t)fl * 8) = th.s;
        *(bf16x8_t*)(Alo + (size_t)fl * 8) = tl.s;
      } else {
        const unsigned short* src = (const unsigned short*)Aq + (size_t)(m0 + row) * K + kk;
        *(bf16x8_t*)(Ahi + (size_t)fl * 8) = *(const bf16x8_t*)src;
      }
    }
#pragma unroll
    for (int p = 0; p < 4; ++p) {
      int fl = p * 256 + tid;
      int row = fl & 127, ko = (fl >> 7) & 3, kit = fl >> 9;
      int kk = kc + kit * 32 + ko * 8;
      const float* src = Wf + (size_t)(n0 + row) * K + kk;
      union { bf16x8_t s; unsigned short u[8]; } th, tl;
#pragma unroll
      for (int e = 0; e < 8; ++e) {
        float v = src[e];
        unsigned short h = f2bf(v);
        th.u[e] = (short)h;
        tl.u[e] = (short)f2bf(v - bf2f(h));
      }
      *(bf16x8_t*)(Bhi + (size_t)fl * 8) = th.s;
      *(bf16x8_t*)(Blo + (size_t)fl * 8) = tl.s;
    }
    __syncthreads();
#pragma unroll
    for (int kit = 0; kit < 2; ++kit) {
      bf16x8_t bhf[4], blf[4];
#pragma unroll
      for (int n = 0; n < 4; ++n) {
        int br = wn * 64 + n * 16 + lm;
        bhf[n] = *(const bf16x8_t*)(Bhi + ((size_t)(kit * 4 + lk) * 128 + br) * 8);
        blf[n] = *(const bf16x8_t*)(Blo + ((size_t)(kit * 4 + lk) * 128 + br) * 8);
      }
#pragma unroll
      for (int m = 0; m < 4; ++m) {
        int ar = wm * 64 + m * 16 + lm;
        bf16x8_t a = *(const bf16x8_t*)(Ahi + ((size_t)(kit * 4 + lk) * 128 + ar) * 8);
        bf16x8_t al;
        if (ASPLIT) al = *(const bf16x8_t*)(Alo + ((size_t)(kit * 4 + lk) * 128 + ar) * 8);
#pragma unroll
        for (int n = 0; n < 4; ++n) {
          acc[m][n] = mfma16(a, bhf[n], acc[m][n]);
          acc[m][n] = mfma16(a, blf[n], acc[m][n]);
          if (ASPLIT) acc[m][n] = mfma16(al, bhf[n], acc[m][n]);
        }
      }
    }
  }
#pragma unroll
  for (int n = 0; n < 4; ++n) {
    int col = n0 + wn * 64 + n * 16 + lm;
    float bv = bias1[col];
    if (bias2 != nullptr) bv += bias2[col];
#pragma unroll
    for (int m = 0; m < 4; ++m) {
#pragma unroll
      for (int r = 0; r < 4; ++r) {
        int row = m0 + wm * 64 + m * 16 + lk * 4 + r;
        float v = acc[m][n][r] + bv;
        if (OUTBF16)
          ((unsigned short*)Cq)[(size_t)row * N + col] = f2bf(v);
        else
          ((float*)Cq)[(size_t)row * N + col] = v;
      }
    }
  }
}

// x pre-split: fp32 -> (hi, lo) bf16 planes.
__global__ __launch_bounds__(256) void splitx_k(const float* __restrict__ x,
                                               unsigned short* __restrict__ xhi,
                                               unsigned short* __restrict__ xlo) {
  int i = (blockIdx.x * 256 + threadIdx.x) * 4;
  float4 v = *(const float4*)(x + i);
  ushort4 h, lo;
  h.x = f2bf(v.x); lo.x = f2bf(v.x - bf2f(h.x));
  h.y = f2bf(v.y); lo.y = f2bf(v.y - bf2f(h.y));
  h.z = f2bf(v.z); lo.z = f2bf(v.z - bf2f(h.z));
  h.w = f2bf(v.w); lo.w = f2bf(v.w - bf2f(h.w));
  *(ushort4*)(xhi + i) = h;
  *(ushort4*)(xlo + i) = lo;
}

// ---------------------------------------------------------------------------
// Persistent pipelined RNN. 256 blocks: l = bid>>6, me = (bid&63)>>2,
// bg = bid&3; 64 neurons x 16 batches per block; group (l,bg) = 16 members.
// Round-7 per-step schedule (fast path):
//   [htmp pre-gathered last iter] stage h | sync | a0 MFMA | dn-wait |
//   epilogue stores | pre-issue seq gather | sync (drains stores+gather) |
//   publish t+2 | ISSUE own snapshot (no wait) | deferred s3 |
//   stage seq | sync | a3 MFMA (snapshot completes underneath) |
//   ballot snapshot -> pre-gather h(t+1)
// Slow paths fall back to blocking polls (round-5 behavior). Wait conditions
// are unchanged; only observation points moved (monotone counters => safe).
// ---------------------------------------------------------------------------
__global__ __launch_bounds__(256, 1) void rnn_k(
    const float* __restrict__ hidden,
    const float* __restrict__ Wih0, const float* __restrict__ Whh0,
    const float* __restrict__ bih0, const float* __restrict__ bhh0,
    const float* __restrict__ WihL, const float* __restrict__ WhhL,
    const float* __restrict__ bihL, const float* __restrict__ bhhL,
    const unsigned short* __restrict__ xhi, const unsigned short* __restrict__ xlo,
    unsigned short* __restrict__ ring, unsigned short* __restrict__ seqr,
    unsigned short* __restrict__ s3, float* __restrict__ hn,
    unsigned* __restrict__ prog) {
  extern __shared__ char lds[];  // 64 KB: h 32K | seq 32K
  char* ldsH = lds;
  char* ldsS = lds + 32768;
  const int tid = threadIdx.x;
  const int wave = tid >> 6, lane = tid & 63;
  const int lm = lane & 15, lk = lane >> 4;
  const int bid = blockIdx.x;
  const int l = bid >> 6;
  const int sub = bid & 63;
  const int me = sub >> 2, bg = sub & 3;
  const int g = l * 4 + bg;
  const int j0 = me * 64 + wave * 16;
  const int j = j0 + lm;

  // ---- weight fragments (bf16-hi) in registers
  const float* Whh = (l == 0) ? Whh0 : WhhL + (size_t)(l - 1) * H_ * H_;
  bf16x8_t bh[32];
#pragma unroll
  for (int kit = 0; kit < 32; ++kit) {
    const float* src = Whh + (size_t)j * H_ + kit * 32 + lk * 8;
    union { bf16x8_t s; unsigned short u[8]; } th;
#pragma unroll
    for (int e = 0; e < 8; ++e) th.u[e] = (short)f2bf(src[e]);
    bh[kit] = th.s;
  }
  bf16x8_t bw[32];
  bf16x8_t w0h[4], w0l[4];
  if (l > 0) {
    const float* Wih = WihL + (size_t)(l - 1) * H_ * H_;
#pragma unroll
    for (int kit = 0; kit < 32; ++kit) {
      const float* src = Wih + (size_t)j * H_ + kit * 32 + lk * 8;
      union { bf16x8_t s; unsigned short u[8]; } th;
#pragma unroll
      for (int e = 0; e < 8; ++e) th.u[e] = (short)f2bf(src[e]);
      bw[kit] = th.s;
    }
  } else {
#pragma unroll
    for (int kit = 0; kit < 4; ++kit) {
      const float* src = Wih0 + (size_t)j * I_ + kit * 32 + lk * 8;
      union { bf16x8_t s; unsigned short u[8]; } th, tl;
#pragma unroll
      for (int e = 0; e < 8; ++e) {
        float v = src[e];
        unsigned short h = f2bf(v);
        th.u[e] = (short)h;
        tl.u[e] = (short)f2bf(v - bf2f(h));
      }
      w0h[kit] = th.s; w0l[kit] = tl.s;
    }
  }
  float bias = (l == 0) ? (bih0[j] + bhh0[j])
                        : (bihL[(size_t)(l - 1) * H_ + j] + bhhL[(size_t)(l - 1) * H_ + j]);

  // ---- init: h0 -> ring slot 1 (this block's 64-neuron portion, u32-packed)
  {
    unsigned* r1 = (unsigned*)(ring + ((size_t)(l * 2 + 1) * 4 + bg) * 16384);
#pragma unroll
    for (int q = 0; q < 2; ++q) {
      int s = q * 256 + tid;  // [0,512) -> u32 idx me*512 + s
      int J = s >> 6, b16 = (s >> 2) & 15, h4 = s & 3;
      int jj = me * 64 + J * 8 + h4 * 2;
      const float* hp = hidden + (size_t)l * B_ * H_ + (bg * 16 + b16) * H_ + jj;
      unsigned p0 = f2bf(hp[0]), p1 = f2bf(hp[1]);
      ast32(r1 + me * 512 + s, p0 | (p1 << 16));
    }
  }
  __syncthreads();  // drains vmcnt for the whole block
  if (tid == 0) ast32(prog + (size_t)(g * 16 + me) * 32, 1u);

  const unsigned* ownB = prog + (size_t)g * 512;
  const unsigned* upB = prog + (size_t)((l - 1) * 4 + bg) * 512;  // l>0 only
  const unsigned* dnB = prog + (size_t)((l + 1) * 4 + bg) * 512;  // l<3 only
  unsigned upMin = 1, dnMin = 1;
  f32x4_t a3s = {0.f, 0.f, 0.f, 0.f};
  unsigned long long htmp[16];
  unsigned long long stmp[16];
  bf16x8_t xh4[4], xl4[4];
  bool hPre = false, sPre = false;
  unsigned snap = 0;

  auto gatherH = [&](int tt) {
    const unsigned long long* hp = (const unsigned long long*)(ring +
        ((size_t)(l * 2 + ((tt & 1) ^ 1)) * 4 + bg) * 16384);
#pragma unroll
    for (int i = 0; i < 16; ++i) htmp[i] = ald64(hp + i * 256 + tid);
  };
  auto gatherSeq = [&](int tt) {
    const unsigned long long* sp = (const unsigned long long*)(seqr +
        ((size_t)((l - 1) * D_ + (tt & (D_ - 1))) * 4 + bg) * 16384);
#pragma unroll
    for (int i = 0; i < 16; ++i) stmp[i] = ald64(sp + i * 256 + tid);
  };
  auto gatherX = [&](int tt) {
    const int b = bg * 16 + lm;
#pragma unroll
    for (int kit = 0; kit < 4; ++kit) {
      const size_t xo = ((size_t)b * T_ + tt) * I_ + kit * 32 + lk * 8;
      xh4[kit] = *(const bf16x8_t*)(xhi + xo);
      xl4[kit] = *(const bf16x8_t*)(xlo + xo);
    }
  };

  // Finish the input-projection precompute for step tt (fills a3s). The
  // own-group snapshot (issued at publish) is NOT consumed until after the
  // a3 accumulation, so its L3 latency hides under seq-gather+stage+MFMAs.
  // Only then ballot-check it and, on success, pre-gather h(tt) — replacing
  // the loop-top poll. (R6 checked it first: serial 700cy every step.)
  auto finishPre = [&](int tt) {
    if (l > 0) {
      if (!sPre) {
        if (upMin < (unsigned)(tt + 2)) upMin = wait_ge(upB, (unsigned)(tt + 2));
        asm volatile("" ::: "memory");
        gatherSeq(tt);
      }
      unsigned long long* dsp = (unsigned long long*)ldsS;
#pragma unroll
      for (int i = 0; i < 16; ++i) dsp[i * 256 + tid] = stmp[i];
      __syncthreads();
      f32x4_t x0 = {0.f,0.f,0.f,0.f}, x1 = {0.f,0.f,0.f,0.f};
      f32x4_t x2 = {0.f,0.f,0.f,0.f}, x3 = {0.f,0.f,0.f,0.f};
#pragma unroll
      for (int kit = 0; kit < 32; ++kit) {
        const int fo = ((kit * 4 + lk) * 16 + lm) * 16;
        bf16x8_t as = *(const bf16x8_t*)(ldsS + fo);
        if ((kit & 3) == 0)      x0 = mfma16(as, bw[kit], x0);
        else if ((kit & 3) == 1) x1 = mfma16(as, bw[kit], x1);
        else if ((kit & 3) == 2) x2 = mfma16(as, bw[kit], x2);
        else                     x3 = mfma16(as, bw[kit], x3);
      }
      a3s = (x0 + x1) + (x2 + x3);
    } else {
      f32x4_t x0 = {0.f,0.f,0.f,0.f}, x1 = {0.f,0.f,0.f,0.f}, x2 = {0.f,0.f,0.f,0.f};
#pragma unroll
      for (int kit = 0; kit < 4; ++kit) {
        x0 = mfma16(xh4[kit], w0h[kit], x0);
        x1 = mfma16(xl4[kit], w0h[kit], x1);
        x2 = mfma16(xh4[kit], w0l[kit], x2);
      }
      a3s = (x0 + x1) + x2;
    }
    // Snapshot consumed HERE (first use -> waitcnt lands after the MFMAs).
    // Need all peers >= tt+1 (monotone counters -> conservative & safe).
    hPre = (__ballot(snap < (unsigned)(tt + 1)) == 0ull);
    asm volatile("" ::: "memory");
    if (hPre) gatherH(tt);
  };

  // ---- prologue: mirror of loop tail for t = 0
  snap = aldc(ownB + (tid & 15) * 32);
  sPre = false;
  if (l == 0) { gatherX(0); sPre = true; }
  finishPre(0);

  for (int t = 0; t < T_; ++t) {
    // A. own-group barrier slow path (snapshot missed) + h gather
    if (!hPre) {
      wait_all(ownB, (unsigned)(t + 1));
      asm volatile("" ::: "memory");
      gatherH(t);
    }
    // B. stage h -> LDS (frag order preserved)
    {
      unsigned long long* dh = (unsigned long long*)ldsH;
#pragma unroll
      for (int i = 0; i < 16; ++i) dh[i * 256 + tid] = htmp[i];
    }
    __syncthreads();
    // C. a0 = h @ Whh^T (4 independent accumulation chains)
    f32x4_t h0 = {0.f,0.f,0.f,0.f}, h1 = {0.f,0.f,0.f,0.f};
    f32x4_t h2 = {0.f,0.f,0.f,0.f}, h3 = {0.f,0.f,0.f,0.f};
#pragma unroll
    for (int kit = 0; kit < 32; ++kit) {
      const int fo = ((kit * 4 + lk) * 16 + lm) * 16;
      bf16x8_t ah = *(const bf16x8_t*)(ldsH + fo);
      if ((kit & 3) == 0)      h0 = mfma16(ah, bh[kit], h0);
      else if ((kit & 3) == 1) h1 = mfma16(ah, bh[kit], h1);
      else if ((kit & 3) == 2) h2 = mfma16(ah, bh[kit], h2);
      else                     h3 = mfma16(ah, bh[kit], h3);
    }
    f32x4_t a0 = (h0 + h1) + (h2 + h3);
    // D. downstream back-pressure before overwriting seq slot (cached)
    if (l < 3 && t >= D_ && dnMin < (unsigned)(t - D_ + 2))
      dnMin = wait_ge(dnB, (unsigned)(t - D_ + 2));
    // E. epilogue: lane holds (j, b = bg*16 + lk*4 + r); u32 pair-packed stores
    unsigned* rwu = (unsigned*)(ring + ((size_t)(l * 2 + (t & 1)) * 4 + bg) * 16384);
    unsigned* swu = (unsigned*)(seqr + ((size_t)(l * D_ + (t & (D_ - 1))) * 4 + bg) * 16384);
    unsigned hi4[4];
#pragma unroll
    for (int r = 0; r < 4; ++r) {
      const int b15 = lk * 4 + r;
      float v = a0[r] + a3s[r] + bias;
      v = fmaxf(v, 0.f);
      unsigned hi = f2bf(v);
      hi4[r] = hi;
      unsigned other = (unsigned)__shfl_xor((int)hi, 1);
      if (!(lm & 1)) {
        const unsigned pk = hi | (other << 16);
        const int p32 = ((j >> 3) * 16 + b15) * 4 + ((j & 7) >> 1);
        ast32(rwu + p32, pk);
        if (l < 3) ast32(swu + p32, pk);
      }
      if (t == T_ - 1) hn[(size_t)l * B_ * H_ + (bg * 16 + b15) * H_ + j] = v;
    }
    // E2. pre-issue next-step seq/x gather: overlaps the release store-drain
    sPre = false;
    if (t + 1 < T_) {
      if (l > 0) {
        if (upMin >= (unsigned)(t + 3)) { gatherSeq(t + 1); sPre = true; }
      } else {
        gatherX(t + 1); sPre = true;
      }
    }
    // F. release: __syncthreads drains all waves' stores (and pre-gathers),
    // then publish progress.
    __syncthreads();
    if (tid == 0) ast32(prog + (size_t)(g * 16 + me) * 32, (unsigned)(t + 2));
    // G. issue (not wait) early snapshot of own-group counters for t+1
    snap = aldc(ownB + (tid & 15) * 32);
    // H. deferred scatter stores (not needed by peers; off the publish path)
    if (l == 3) {
#pragma unroll
      for (int r = 0; r < 4; ++r)
        s3[((size_t)(bg * 16 + lk * 4 + r) * T_ + t) * H_ + j] = (unsigned short)hi4[r];
    }
    // I. finish precompute for t+1; snapshot consumed at its end
    if (t + 1 < T_) finishPre(t + 1);
  }
}

// ---------------------------------------------------------------------------
// ws layout: prog 32KB (16 groups x 16 members x 128B) | pad to 64K |
// ring 1MB (u16 [l][slot2][bg][16384]) | seqr 12MB | s3 64MB | xhi 8MB |
// xlo 8MB  => ~93 MB.
// ---------------------------------------------------------------------------
extern "C" void kernel_launch(void* const* d_in, const int* in_sizes, int n_in,
                              void* d_out, int out_size, void* d_ws, size_t ws_size,
                              hipStream_t stream) {
  const float* x = (const float*)d_in[0];
  const float* hidden = (const float*)d_in[1];
  const float* Wih0 = (const float*)d_in[2];
  const float* Whh0 = (const float*)d_in[3];
  const float* bih0 = (const float*)d_in[4];
  const float* bhh0 = (const float*)d_in[5];
  const float* WihL = (const float*)d_in[6];
  const float* WhhL = (const float*)d_in[7];
  const float* bihL = (const float*)d_in[8];
  const float* bhhL = (const float*)d_in[9];
  const float* Wfc = (const float*)d_in[10];
  const float* bfc = (const float*)d_in[11];
  float* out = (float*)d_out;
  float* hn = out + (size_t)M_ * O_;

  char* ws = (char*)d_ws;
  unsigned* prog = (unsigned*)ws;
  unsigned short* ring = (unsigned short*)(ws + 65536);
  unsigned short* seqr = (unsigned short*)(ws + 65536 + (1u << 20));
  unsigned short* s3 = (unsigned short*)(ws + 65536 + (1u << 20) + (12u << 20));
  unsigned short* xhi = (unsigned short*)(ws + 65536 + (1u << 20) + (12u << 20) + (64u << 20));
  unsigned short* xlo = xhi + (size_t)B_ * T_ * I_;

  hipMemsetAsync(ws, 0, 65536, stream);  // progress counters
  splitx_k<<<(B_ * T_ * I_) / 1024, 256, 0, stream>>>(x, xhi, xlo);

  hipFuncSetAttribute((const void*)rnn_k, hipFuncAttributeMaxDynamicSharedMemorySize,
                      64 * 1024);
  rnn_k<<<256, 256, 64 * 1024, stream>>>(hidden, Wih0, Whh0, bih0, bhh0,
                                         WihL, WhhL, bihL, bhhL, xhi, xlo,
                                         ring, seqr, s3, hn, prog);

  gemm_k<H_, O_, false, false><<<dim3(O_ / 128, M_ / 128), 256, 48 * 1024, stream>>>(
      (const void*)s3, Wfc, bfc, nullptr, (void*)out);
}

// Round 12
// 2152.344 us; speedup vs baseline: 1.2091x; 1.1283x over previous
//
#include <hip/hip_runtime.h>

// SimpleRNN: B=64,T=512,I=128,H=1024,L=4,O=128
// Round 8: revert to the proven R5 structure (1872us). R6/R7 regressed
// (2526/2346us) because they pre-issued the 32KB seq gather BEFORE the
// release __syncthreads — the compiler's vmcnt(0) drain before s_barrier put
// the gather latency on the publish path, delaying every peer. R8 keeps R5
// verbatim and adds ONE change: a 16-counter own-group snapshot issued right
// after publish and consumed at the END of precompute (after the a3 MFMAs,
// latency hidden); on ballot hit the loop-top blocking poll is skipped.
#define B_ 64
#define T_ 512
#define I_ 128
#define H_ 1024
#define L_ 4
#define O_ 128
#define M_ (B_ * T_)
#define D_ 32  // inter-layer seq ring depth (steps)

typedef __attribute__((ext_vector_type(8))) short bf16x8_t;
typedef __attribute__((ext_vector_type(4))) float f32x4_t;

__device__ __forceinline__ unsigned short f2bf(float x) {
  unsigned int u = __builtin_bit_cast(unsigned int, x);
  u += 0x7FFFu + ((u >> 16) & 1u);
  return (unsigned short)(u >> 16);
}
__device__ __forceinline__ float bf2f(unsigned short h) {
  return __builtin_bit_cast(float, ((unsigned int)h) << 16);
}
__device__ __forceinline__ f32x4_t mfma16(bf16x8_t a, bf16x8_t b, f32x4_t c) {
  return __builtin_amdgcn_mfma_f32_16x16x32_bf16(a, b, c, 0, 0, 0);
}

// Relaxed agent-scope atomics (served at device coherence point; proven r2).
__device__ __forceinline__ unsigned aldc(const unsigned* p) {
  return __hip_atomic_load(p, __ATOMIC_RELAXED, __HIP_MEMORY_SCOPE_AGENT);
}
__device__ __forceinline__ unsigned long long ald64(const unsigned long long* p) {
  return __hip_atomic_load(p, __ATOMIC_RELAXED, __HIP_MEMORY_SCOPE_AGENT);
}
__device__ __forceinline__ void ast32(unsigned* p, unsigned v) {
  __hip_atomic_store(p, v, __ATOMIC_RELAXED, __HIP_MEMORY_SCOPE_AGENT);
}

// All threads poll 16 member counters (stride 32 u32 = 128B lines) until all
// >= target; returns wave-uniform min (lanes 16.. mirror members 0-15).
__device__ __forceinline__ unsigned wait_ge(const unsigned* base, unsigned target) {
  const int i = threadIdx.x & 15;
  unsigned v;
  while (true) {
    v = aldc(base + i * 32);
    if (__ballot(v < target) == 0ull) break;
    __builtin_amdgcn_s_sleep(2);
  }
  unsigned mn = v;
  mn = min(mn, (unsigned)__shfl_xor((int)mn, 1));
  mn = min(mn, (unsigned)__shfl_xor((int)mn, 2));
  mn = min(mn, (unsigned)__shfl_xor((int)mn, 4));
  mn = min(mn, (unsigned)__shfl_xor((int)mn, 8));
  mn = min(mn, (unsigned)__shfl_xor((int)mn, 16));
  mn = min(mn, (unsigned)__shfl_xor((int)mn, 32));
  return mn;
}

// Own-group barrier poll: no min-reduce needed.
__device__ __forceinline__ void wait_all(const unsigned* base, unsigned target) {
  const int i = threadIdx.x & 15;
  while (true) {
    unsigned v = aldc(base + i * 32);
    if (__ballot(v < target) == 0ull) break;
    __builtin_amdgcn_s_sleep(2);
  }
}

// ---------------------------------------------------------------------------
// MFMA GEMM (round-1, proven) — used only for the final FC here.
// ---------------------------------------------------------------------------
template <int K, int N, bool ASPLIT, bool OUTBF16>
__global__ __launch_bounds__(256, 2) void gemm_k(
    const void* __restrict__ Aq, const float* __restrict__ Wf,
    const float* __restrict__ bias1, const float* __restrict__ bias2,
    void* __restrict__ Cq) {
  extern __shared__ unsigned short smem[];
  unsigned short* Ahi = smem;
  unsigned short* Alo = Ahi + (ASPLIT ? 8192 : 0);
  unsigned short* Bhi = Alo + 8192;
  unsigned short* Blo = Bhi + 8192;

  const int tid = threadIdx.x;
  const int wave = tid >> 6, lane = tid & 63;
  const int wm = wave >> 1, wn = wave & 1;
  const int lm = lane & 15, lk = lane >> 4;
  const int m0 = blockIdx.y * 128, n0 = blockIdx.x * 128;

  f32x4_t acc[4][4] = {};

  for (int kc = 0; kc < K; kc += 64) {
    __syncthreads();
#pragma unroll
    for (int p = 0; p < 4; ++p) {
      int fl = p * 256 + tid;
      int row = fl & 127, ko = (fl >> 7) & 3, kit = fl >> 9;
      int kk = kc + kit * 32 + ko * 8;
      if (ASPLIT) {
        const float* src = (const float*)Aq + (size_t)(m0 + row) * K + kk;
        union { bf16x8_t s; unsigned short u[8]; } th, tl;
#pragma unroll
        for (int e = 0; e < 8; ++e) {
          float v = src[e];
          unsigned short h = f2bf(v);
          th.u[e] = (short)h;
          tl.u[e] = (short)f2bf(v - bf2f(h));
        }
        *(bf16x8_t*)(Ahi + (size_t)fl * 8) = th.s;
        *(bf16x8_t*)(Alo + (size_t)fl * 8) = tl.s;
      } else {
        const unsigned short* src = (const unsigned short*)Aq + (size_t)(m0 + row) * K + kk;
        *(bf16x8_t*)(Ahi + (size_t)fl * 8) = *(const bf16x8_t*)src;
      }
    }
#pragma unroll
    for (int p = 0; p < 4; ++p) {
      int fl = p * 256 + tid;
      int row = fl & 127, ko = (fl >> 7) & 3, kit = fl >> 9;
      int kk = kc + kit * 32 + ko * 8;
      const float* src = Wf + (size_t)(n0 + row) * K + kk;
      union { bf16x8_t s; unsigned short u[8]; } th, tl;
#pragma unroll
      for (int e = 0; e < 8; ++e) {
        float v = src[e];
        unsigned short h = f2bf(v);
        th.u[e] = (short)h;
        tl.u[e] = (short)f2bf(v - bf2f(h));
      }
      *(bf16x8_t*)(Bhi + (size_t)fl * 8) = th.s;
      *(bf16x8_t*)(Blo + (size_t)fl * 8) = tl.s;
    }
    __syncthreads();
#pragma unroll
    for (int kit = 0; kit < 2; ++kit) {
      bf16x8_t bhf[4], blf[4];
#pragma unroll
      for (int n = 0; n < 4; ++n) {
        int br = wn * 64 + n * 16 + lm;
        bhf[n] = *(const bf16x8_t*)(Bhi + ((size_t)(kit * 4 + lk) * 128 + br) * 8);
        blf[n] = *(const bf16x8_t*)(Blo + ((size_t)(kit * 4 + lk) * 128 + br) * 8);
      }
#pragma unroll
      for (int m = 0; m < 4; ++m) {
        int ar = wm * 64 + m * 16 + lm;
        bf16x8_t a = *(const bf16x8_t*)(Ahi + ((size_t)(kit * 4 + lk) * 128 + ar) * 8);
        bf16x8_t al;
        if (ASPLIT) al = *(const bf16x8_t*)(Alo + ((size_t)(kit * 4 + lk) * 128 + ar) * 8);
#pragma unroll
        for (int n = 0; n < 4; ++n) {
          acc[m][n] = mfma16(a, bhf[n], acc[m][n]);
          acc[m][n] = mfma16(a, blf[n], acc[m][n]);
          if (ASPLIT) acc[m][n] = mfma16(al, bhf[n], acc[m][n]);
        }
      }
    }
  }
#pragma unroll
  for (int n = 0; n < 4; ++n) {
    int col = n0 + wn * 64 + n * 16 + lm;
    float bv = bias1[col];
    if (bias2 != nullptr) bv += bias2[col];
#pragma unroll
    for (int m = 0; m < 4; ++m) {
#pragma unroll
      for (int r = 0; r < 4; ++r) {
        int row = m0 + wm * 64 + m * 16 + lk * 4 + r;
        float v = acc[m][n][r] + bv;
        if (OUTBF16)
          ((unsigned short*)Cq)[(size_t)row * N + col] = f2bf(v);
        else
          ((float*)Cq)[(size_t)row * N + col] = v;
      }
    }
  }
}

// x pre-split: fp32 -> (hi, lo) bf16 planes.
__global__ __launch_bounds__(256) void splitx_k(const float* __restrict__ x,
                                               unsigned short* __restrict__ xhi,
                                               unsigned short* __restrict__ xlo) {
  int i = (blockIdx.x * 256 + threadIdx.x) * 4;
  float4 v = *(const float4*)(x + i);
  ushort4 h, lo;
  h.x = f2bf(v.x); lo.x = f2bf(v.x - bf2f(h.x));
  h.y = f2bf(v.y); lo.y = f2bf(v.y - bf2f(h.y));
  h.z = f2bf(v.z); lo.z = f2bf(v.z - bf2f(h.z));
  h.w = f2bf(v.w); lo.w = f2bf(v.w - bf2f(h.w));
  *(ushort4*)(xhi + i) = h;
  *(ushort4*)(xlo + i) = lo;
}

// ---------------------------------------------------------------------------
// Persistent pipelined RNN (R5 structure + snapshot poll-skip).
// 256 blocks: l = bid>>6, me = (bid&63)>>2, bg = bid&3; 64 neurons x 16
// batches per block; group (l,bg) = 16 members. Per-step (fast path):
//   [hPre from last iter] (skip poll) | gatherH | stage h | sync | a0 MFMA |
//   epilogue stores | sync | publish t+2 | ISSUE snapshot | deferred s3 |
//   precompute(t+1): up-wait(cached), seq gather, stage, sync, a3 MFMA |
//   ballot snapshot -> hPre for next iteration
// No loads are issued between the epilogue and the release sync (that was
// R6/R7's regression: vmcnt(0)-before-barrier put gather latency on the
// publish path). Miss path = R5 exactly. Monotone counters => skipping the
// poll on a one-iteration-old all-peers-done observation is conservative.
// ---------------------------------------------------------------------------
__global__ __launch_bounds__(256, 1) void rnn_k(
    const float* __restrict__ hidden,
    const float* __restrict__ Wih0, const float* __restrict__ Whh0,
    const float* __restrict__ bih0, const float* __restrict__ bhh0,
    const float* __restrict__ WihL, const float* __restrict__ WhhL,
    const float* __restrict__ bihL, const float* __restrict__ bhhL,
    const unsigned short* __restrict__ xhi, const unsigned short* __restrict__ xlo,
    unsigned short* __restrict__ ring, unsigned short* __restrict__ seqr,
    unsigned short* __restrict__ s3, float* __restrict__ hn,
    unsigned* __restrict__ prog) {
  extern __shared__ char lds[];  // 64 KB: h 32K | seq 32K
  char* ldsH = lds;
  char* ldsS = lds + 32768;
  const int tid = threadIdx.x;
  const int wave = tid >> 6, lane = tid & 63;
  const int lm = lane & 15, lk = lane >> 4;
  const int bid = blockIdx.x;
  const int l = bid >> 6;
  const int sub = bid & 63;
  const int me = sub >> 2, bg = sub & 3;
  const int g = l * 4 + bg;
  const int j0 = me * 64 + wave * 16;
  const int j = j0 + lm;

  // ---- weight fragments (bf16-hi) in registers
  const float* Whh = (l == 0) ? Whh0 : WhhL + (size_t)(l - 1) * H_ * H_;
  bf16x8_t bh[32];
#pragma unroll
  for (int kit = 0; kit < 32; ++kit) {
    const float* src = Whh + (size_t)j * H_ + kit * 32 + lk * 8;
    union { bf16x8_t s; unsigned short u[8]; } th;
#pragma unroll
    for (int e = 0; e < 8; ++e) th.u[e] = (short)f2bf(src[e]);
    bh[kit] = th.s;
  }
  bf16x8_t bw[32];
  bf16x8_t w0h[4], w0l[4];
  if (l > 0) {
    const float* Wih = WihL + (size_t)(l - 1) * H_ * H_;
#pragma unroll
    for (int kit = 0; kit < 32; ++kit) {
      const float* src = Wih + (size_t)j * H_ + kit * 32 + lk * 8;
      union { bf16x8_t s; unsigned short u[8]; } th;
#pragma unroll
      for (int e = 0; e < 8; ++e) th.u[e] = (short)f2bf(src[e]);
      bw[kit] = th.s;
    }
  } else {
#pragma unroll
    for (int kit = 0; kit < 4; ++kit) {
      const float* src = Wih0 + (size_t)j * I_ + kit * 32 + lk * 8;
      union { bf16x8_t s; unsigned short u[8]; } th, tl;
#pragma unroll
      for (int e = 0; e < 8; ++e) {
        float v = src[e];
        unsigned short h = f2bf(v);
        th.u[e] = (short)h;
        tl.u[e] = (short)f2bf(v - bf2f(h));
      }
      w0h[kit] = th.s; w0l[kit] = tl.s;
    }
  }
  float bias = (l == 0) ? (bih0[j] + bhh0[j])
                        : (bihL[(size_t)(l - 1) * H_ + j] + bhhL[(size_t)(l - 1) * H_ + j]);

  // ---- init: h0 -> ring slot 1 (this block's 64-neuron portion, u32-packed)
  {
    unsigned* r1 = (unsigned*)(ring + ((size_t)(l * 2 + 1) * 4 + bg) * 16384);
#pragma unroll
    for (int q = 0; q < 2; ++q) {
      int s = q * 256 + tid;  // [0,512) -> u32 idx me*512 + s
      int J = s >> 6, b16 = (s >> 2) & 15, h4 = s & 3;
      int jj = me * 64 + J * 8 + h4 * 2;
      const float* hp = hidden + (size_t)l * B_ * H_ + (bg * 16 + b16) * H_ + jj;
      unsigned p0 = f2bf(hp[0]), p1 = f2bf(hp[1]);
      ast32(r1 + me * 512 + s, p0 | (p1 << 16));
    }
  }
  __syncthreads();  // drains vmcnt for the whole block
  if (tid == 0) ast32(prog + (size_t)(g * 16 + me) * 32, 1u);

  const unsigned* ownB = prog + (size_t)g * 512;
  const unsigned* upB = prog + (size_t)((l - 1) * 4 + bg) * 512;  // l>0 only
  const unsigned* dnB = prog + (size_t)((l + 1) * 4 + bg) * 512;  // l<3 only
  unsigned upMin = 1, dnMin = 1;
  f32x4_t a3s = {0.f, 0.f, 0.f, 0.f};
  unsigned long long htmp[16];
  unsigned long long stmp[16];
  bool hPre = false;
  unsigned snap = 0;

  auto gatherH = [&](int tt) {
    const unsigned long long* hp = (const unsigned long long*)(ring +
        ((size_t)(l * 2 + ((tt & 1) ^ 1)) * 4 + bg) * 16384);
#pragma unroll
    for (int i = 0; i < 16; ++i) htmp[i] = ald64(hp + i * 256 + tid);
  };
  auto gatherSeq = [&](int tt) {
    const unsigned long long* sp = (const unsigned long long*)(seqr +
        ((size_t)((l - 1) * D_ + (tt & (D_ - 1))) * 4 + bg) * 16384);
#pragma unroll
    for (int i = 0; i < 16; ++i) stmp[i] = ald64(sp + i * 256 + tid);
  };

  // Input-projection precompute for step tt (fills a3s), R5 structure: the
  // seq gather is issued HERE (after publish), never before the release sync.
  // At the end, consume the snapshot (issued at publish; latency hidden under
  // the gather/stage/MFMAs) and decide whether the loop-top poll can be
  // skipped. Need all peers >= tt+1 (monotone counters -> conservative).
  auto precompute = [&](int tt) {
    if (l > 0) {
      if (upMin < (unsigned)(tt + 2)) upMin = wait_ge(upB, (unsigned)(tt + 2));
      asm volatile("" ::: "memory");
      gatherSeq(tt);
      unsigned long long* dsp = (unsigned long long*)ldsS;
#pragma unroll
      for (int i = 0; i < 16; ++i) dsp[i * 256 + tid] = stmp[i];
      __syncthreads();
      f32x4_t xa = {0.f, 0.f, 0.f, 0.f}, xb = {0.f, 0.f, 0.f, 0.f};
#pragma unroll
      for (int kit = 0; kit < 32; ++kit) {
        const int fo = ((kit * 4 + lk) * 16 + lm) * 16;
        bf16x8_t as = *(const bf16x8_t*)(ldsS + fo);
        if (kit & 1) xb = mfma16(as, bw[kit], xb);
        else         xa = mfma16(as, bw[kit], xa);
      }
      a3s = xa + xb;
    } else {
      const int b = bg * 16 + lm;
      f32x4_t xa = {0.f, 0.f, 0.f, 0.f}, xb = {0.f, 0.f, 0.f, 0.f};
#pragma unroll
      for (int kit = 0; kit < 4; ++kit) {
        const size_t xo = ((size_t)b * T_ + tt) * I_ + kit * 32 + lk * 8;
        bf16x8_t xh = *(const bf16x8_t*)(xhi + xo);
        bf16x8_t xl = *(const bf16x8_t*)(xlo + xo);
        xa = mfma16(xh, w0h[kit], xa);
        xb = mfma16(xl, w0h[kit], xb);
        xa = mfma16(xh, w0l[kit], xa);
      }
      a3s = xa + xb;
    }
    // Snapshot consumed here (first use of snap -> waitcnt lands after MFMAs)
    hPre = (__ballot(snap < (unsigned)(tt + 1)) == 0ull);
  };

  // ---- prologue: snapshot after init-publish, then precompute for t = 0
  snap = aldc(ownB + (tid & 15) * 32);
  precompute(0);

  for (int t = 0; t < T_; ++t) {
    // A. downstream back-pressure before overwriting seq slot (cached)
    if (l < 3 && t >= D_) {
      if (dnMin < (unsigned)(t - D_ + 2)) dnMin = wait_ge(dnB, (unsigned)(t - D_ + 2));
    }
    // B. own-group barrier: skipped when last iteration's snapshot already
    // showed all peers >= t+1; otherwise blocking poll (R5 path).
    if (!hPre) wait_all(ownB, (unsigned)(t + 1));
    asm volatile("" ::: "memory");
    // C. h slice gather (32 KB bf16-hi)
    gatherH(t);
    // D. stage h -> LDS (frag order preserved)
    {
      unsigned long long* dh = (unsigned long long*)ldsH;
#pragma unroll
      for (int i = 0; i < 16; ++i) dh[i * 256 + tid] = htmp[i];
    }
    __syncthreads();
    // E. a0 = h @ Whh^T (2 independent accumulation chains, R5)
    f32x4_t h0a = {0.f, 0.f, 0.f, 0.f}, h0b = {0.f, 0.f, 0.f, 0.f};
#pragma unroll
    for (int kit = 0; kit < 32; ++kit) {
      const int fo = ((kit * 4 + lk) * 16 + lm) * 16;
      bf16x8_t ah = *(const bf16x8_t*)(ldsH + fo);
      if (kit & 1) h0b = mfma16(ah, bh[kit], h0b);
      else         h0a = mfma16(ah, bh[kit], h0a);
    }
    // F. epilogue: lane holds (j, b = bg*16 + lk*4 + r); u32 pair-packed stores
    unsigned* rwu = (unsigned*)(ring + ((size_t)(l * 2 + (t & 1)) * 4 + bg) * 16384);
    unsigned* swu = (unsigned*)(seqr + ((size_t)(l * D_ + (t & (D_ - 1))) * 4 + bg) * 16384);
    unsigned hi4[4];
#pragma unroll
    for (int r = 0; r < 4; ++r) {
      const int b15 = lk * 4 + r;
      float v = h0a[r] + h0b[r] + a3s[r] + bias;
      v = fmaxf(v, 0.f);
      unsigned hi = f2bf(v);
      hi4[r] = hi;
      unsigned other = (unsigned)__shfl_xor((int)hi, 1);
      if (!(lm & 1)) {
        const unsigned pk = hi | (other << 16);
        const int p32 = ((j >> 3) * 16 + b15) * 4 + ((j & 7) >> 1);
        ast32(rwu + p32, pk);
        if (l < 3) ast32(swu + p32, pk);
      }
      if (t == T_ - 1) hn[(size_t)l * B_ * H_ + (bg * 16 + b15) * H_ + j] = v;
    }
    // G. release: __syncthreads drains all waves' stores, then publish.
    // (No loads issued between F and here — that was R6/R7's regression.)
    __syncthreads();
    if (tid == 0) ast32(prog + (size_t)(g * 16 + me) * 32, (unsigned)(t + 2));
    // H. issue (not consume) the own-group snapshot for next iteration
    snap = aldc(ownB + (tid & 15) * 32);
    // I. deferred scatter stores (not needed by peers; off the publish path)
    if (l == 3) {
#pragma unroll
      for (int r = 0; r < 4; ++r)
        s3[((size_t)(bg * 16 + lk * 4 + r) * T_ + t) * H_ + j] = (unsigned short)hi4[r];
    }
    // J. precompute a3s for t+1; snapshot consumed at its end
    if (t + 1 < T_) precompute(t + 1);
  }
}

// ---------------------------------------------------------------------------
// ws layout: prog 32KB (16 groups x 16 members x 128B) | pad to 64K |
// ring 1MB (u16 [l][slot2][bg][16384]) | seqr 12MB | s3 64MB | xhi 8MB |
// xlo 8MB  => ~93 MB.
// ---------------------------------------------------------------------------
extern "C" void kernel_launch(void* const* d_in, const int* in_sizes, int n_in,
                              void* d_out, int out_size, void* d_ws, size_t ws_size,
                              hipStream_t stream) {
  const float* x = (const float*)d_in[0];
  const float* hidden = (const float*)d_in[1];
  const float* Wih0 = (const float*)d_in[2];
  const float* Whh0 = (const float*)d_in[3];
  const float* bih0 = (const float*)d_in[4];
  const float* bhh0 = (const float*)d_in[5];
  const float* WihL = (const float*)d_in[6];
  const float* WhhL = (const float*)d_in[7];
  const float* bihL = (const float*)d_in[8];
  const float* bhhL = (const float*)d_in[9];
  const float* Wfc = (const float*)d_in[10];
  const float* bfc = (const float*)d_in[11];
  float* out = (float*)d_out;
  float* hn = out + (size_t)M_ * O_;

  char* ws = (char*)d_ws;
  unsigned* prog = (unsigned*)ws;
  unsigned short* ring = (unsigned short*)(ws + 65536);
  unsigned short* seqr = (unsigned short*)(ws + 65536 + (1u << 20));
  unsigned short* s3 = (unsigned short*)(ws + 65536 + (1u << 20) + (12u << 20));
  unsigned short* xhi = (unsigned short*)(ws + 65536 + (1u << 20) + (12u << 20) + (64u << 20));
  unsigned short* xlo = xhi + (size_t)B_ * T_ * I_;

  hipMemsetAsync(ws, 0, 65536, stream);  // progress counters
  splitx_k<<<(B_ * T_ * I_) / 1024, 256, 0, stream>>>(x, xhi, xlo);

  hipFuncSetAttribute((const void*)rnn_k, hipFuncAttributeMaxDynamicSharedMemorySize,
                      64 * 1024);
  rnn_k<<<256, 256, 64 * 1024, stream>>>(hidden, Wih0, Whh0, bih0, bhh0,
                                         WihL, WhhL, bihL, bhhL, xhi, xlo,
                                         ring, seqr, s3, hn, prog);

  gemm_k<H_, O_, false, false><<<dim3(O_ / 128, M_ / 128), 256, 48 * 1024, stream>>>(
      (const void*)s3, Wfc, bfc, nullptr, (void*)out);
}

// Round 16
// 2015.653 us; speedup vs baseline: 1.2911x; 1.0678x over previous
//
#include <hip/hip_runtime.h>

// SimpleRNN: B=64,T=512,I=128,H=1024,L=4,O=128
// Round 9 (3rd resubmit; GPU-acquisition timeouts, kernel never ran).
// EXACT revert to the proven R5 structure (1872us rnn_k) — the R6/R7/R8
// snapshot/pre-issue family all regressed (2526/2346/2070) and is abandoned.
// Single isolated change vs R5: 4 independent MFMA accumulation chains in
// the a0 and a3 loops (dep distance 4*~5cy >= ~16-20cy MFMA latency,
// removing ~400-600cy/step of dependent-issue stall).
#define B_ 64
#define T_ 512
#define I_ 128
#define H_ 1024
#define L_ 4
#define O_ 128
#define M_ (B_ * T_)
#define D_ 32  // inter-layer seq ring depth (steps)

typedef __attribute__((ext_vector_type(8))) short bf16x8_t;
typedef __attribute__((ext_vector_type(4))) float f32x4_t;

__device__ __forceinline__ unsigned short f2bf(float x) {
  unsigned int u = __builtin_bit_cast(unsigned int, x);
  u += 0x7FFFu + ((u >> 16) & 1u);
  return (unsigned short)(u >> 16);
}
__device__ __forceinline__ float bf2f(unsigned short h) {
  return __builtin_bit_cast(float, ((unsigned int)h) << 16);
}
__device__ __forceinline__ f32x4_t mfma16(bf16x8_t a, bf16x8_t b, f32x4_t c) {
  return __builtin_amdgcn_mfma_f32_16x16x32_bf16(a, b, c, 0, 0, 0);
}

// Relaxed agent-scope atomics (served at device coherence point; proven r2).
__device__ __forceinline__ unsigned aldc(const unsigned* p) {
  return __hip_atomic_load(p, __ATOMIC_RELAXED, __HIP_MEMORY_SCOPE_AGENT);
}
__device__ __forceinline__ unsigned long long ald64(const unsigned long long* p) {
  return __hip_atomic_load(p, __ATOMIC_RELAXED, __HIP_MEMORY_SCOPE_AGENT);
}
__device__ __forceinline__ void ast32(unsigned* p, unsigned v) {
  __hip_atomic_store(p, v, __ATOMIC_RELAXED, __HIP_MEMORY_SCOPE_AGENT);
}

// All 256 threads: poll 16 member counters (stride 32 u32 = 128B lines) until
// all >= target; returns the group min (uniform per 16-lane subgroup).
__device__ __forceinline__ unsigned wait_ge(const unsigned* base, unsigned target) {
  const int i = threadIdx.x & 15;
  unsigned v;
  while (true) {
    v = aldc(base + i * 32);
    if (__ballot(v < target) == 0ull) break;
    __builtin_amdgcn_s_sleep(2);
  }
  unsigned mn = v;
  mn = min(mn, (unsigned)__shfl_xor((int)mn, 1));
  mn = min(mn, (unsigned)__shfl_xor((int)mn, 2));
  mn = min(mn, (unsigned)__shfl_xor((int)mn, 4));
  mn = min(mn, (unsigned)__shfl_xor((int)mn, 8));
  return mn;
}

// Own-group barrier poll: no min-reduce needed (value never cached).
__device__ __forceinline__ void wait_all(const unsigned* base, unsigned target) {
  const int i = threadIdx.x & 15;
  while (true) {
    unsigned v = aldc(base + i * 32);
    if (__ballot(v < target) == 0ull) break;
    __builtin_amdgcn_s_sleep(2);
  }
}

// ---------------------------------------------------------------------------
// MFMA GEMM (round-1, proven) — used only for the final FC here.
// ---------------------------------------------------------------------------
template <int K, int N, bool ASPLIT, bool OUTBF16>
__global__ __launch_bounds__(256, 2) void gemm_k(
    const void* __restrict__ Aq, const float* __restrict__ Wf,
    const float* __restrict__ bias1, const float* __restrict__ bias2,
    void* __restrict__ Cq) {
  extern __shared__ unsigned short smem[];
  unsigned short* Ahi = smem;
  unsigned short* Alo = Ahi + (ASPLIT ? 8192 : 0);
  unsigned short* Bhi = Alo + 8192;
  unsigned short* Blo = Bhi + 8192;

  const int tid = threadIdx.x;
  const int wave = tid >> 6, lane = tid & 63;
  const int wm = wave >> 1, wn = wave & 1;
  const int lm = lane & 15, lk = lane >> 4;
  const int m0 = blockIdx.y * 128, n0 = blockIdx.x * 128;

  f32x4_t acc[4][4] = {};

  for (int kc = 0; kc < K; kc += 64) {
    __syncthreads();
#pragma unroll
    for (int p = 0; p < 4; ++p) {
      int fl = p * 256 + tid;
      int row = fl & 127, ko = (fl >> 7) & 3, kit = fl >> 9;
      int kk = kc + kit * 32 + ko * 8;
      if (ASPLIT) {
        const float* src = (const float*)Aq + (size_t)(m0 + row) * K + kk;
        union { bf16x8_t s; unsigned short u[8]; } th, tl;
#pragma unroll
        for (int e = 0; e < 8; ++e) {
          float v = src[e];
          unsigned short h = f2bf(v);
          th.u[e] = (short)h;
          tl.u[e] = (short)f2bf(v - bf2f(h));
        }
        *(bf16x8_t*)(Ahi + (size_t)fl * 8) = th.s;
        *(bf16x8_t*)(Alo + (size_t)fl * 8) = tl.s;
      } else {
        const unsigned short* src = (const unsigned short*)Aq + (size_t)(m0 + row) * K + kk;
        *(bf16x8_t*)(Ahi + (size_t)fl * 8) = *(const bf16x8_t*)src;
      }
    }
#pragma unroll
    for (int p = 0; p < 4; ++p) {
      int fl = p * 256 + tid;
      int row = fl & 127, ko = (fl >> 7) & 3, kit = fl >> 9;
      int kk = kc + kit * 32 + ko * 8;
      const float* src = Wf + (size_t)(n0 + row) * K + kk;
      union { bf16x8_t s; unsigned short u[8]; } th, tl;
#pragma unroll
      for (int e = 0; e < 8; ++e) {
        float v = src[e];
        unsigned short h = f2bf(v);
        th.u[e] = (short)h;
        tl.u[e] = (short)f2bf(v - bf2f(h));
      }
      *(bf16x8_t*)(Bhi + (size_t)fl * 8) = th.s;
      *(bf16x8_t*)(Blo + (size_t)fl * 8) = tl.s;
    }
    __syncthreads();
#pragma unroll
    for (int kit = 0; kit < 2; ++kit) {
      bf16x8_t bhf[4], blf[4];
#pragma unroll
      for (int n = 0; n < 4; ++n) {
        int br = wn * 64 + n * 16 + lm;
        bhf[n] = *(const bf16x8_t*)(Bhi + ((size_t)(kit * 4 + lk) * 128 + br) * 8);
        blf[n] = *(const bf16x8_t*)(Blo + ((size_t)(kit * 4 + lk) * 128 + br) * 8);
      }
#pragma unroll
      for (int m = 0; m < 4; ++m) {
        int ar = wm * 64 + m * 16 + lm;
        bf16x8_t a = *(const bf16x8_t*)(Ahi + ((size_t)(kit * 4 + lk) * 128 + ar) * 8);
        bf16x8_t al;
        if (ASPLIT) al = *(const bf16x8_t*)(Alo + ((size_t)(kit * 4 + lk) * 128 + ar) * 8);
#pragma unroll
        for (int n = 0; n < 4; ++n) {
          acc[m][n] = mfma16(a, bhf[n], acc[m][n]);
          acc[m][n] = mfma16(a, blf[n], acc[m][n]);
          if (ASPLIT) acc[m][n] = mfma16(al, bhf[n], acc[m][n]);
        }
      }
    }
  }
#pragma unroll
  for (int n = 0; n < 4; ++n) {
    int col = n0 + wn * 64 + n * 16 + lm;
    float bv = bias1[col];
    if (bias2 != nullptr) bv += bias2[col];
#pragma unroll
    for (int m = 0; m < 4; ++m) {
#pragma unroll
      for (int r = 0; r < 4; ++r) {
        int row = m0 + wm * 64 + m * 16 + lk * 4 + r;
        float v = acc[m][n][r] + bv;
        if (OUTBF16)
          ((unsigned short*)Cq)[(size_t)row * N + col] = f2bf(v);
        else
          ((float*)Cq)[(size_t)row * N + col] = v;
      }
    }
  }
}

// x pre-split: fp32 -> (hi, lo) bf16 planes.
__global__ __launch_bounds__(256) void splitx_k(const float* __restrict__ x,
                                               unsigned short* __restrict__ xhi,
                                               unsigned short* __restrict__ xlo) {
  int i = (blockIdx.x * 256 + threadIdx.x) * 4;
  float4 v = *(const float4*)(x + i);
  ushort4 h, lo;
  h.x = f2bf(v.x); lo.x = f2bf(v.x - bf2f(h.x));
  h.y = f2bf(v.y); lo.y = f2bf(v.y - bf2f(h.y));
  h.z = f2bf(v.z); lo.z = f2bf(v.z - bf2f(h.z));
  h.w = f2bf(v.w); lo.w = f2bf(v.w - bf2f(h.w));
  *(ushort4*)(xhi + i) = h;
  *(ushort4*)(xlo + i) = lo;
}

// ---------------------------------------------------------------------------
// Persistent pipelined RNN (R5 structure, proven 1872us). 256 blocks:
// l = bid>>6, me = (bid&63)>>2, bg = bid&3; 64 neurons x 16 batches per
// block; group (l,bg) = 16 members. Per-step:
//   dn-wait(cached) | own wait_all | h gather | stage+sync | a0 MFMA |
//   epilogue (ring+seq+s3 stores) | release sync | publish t+2 |
//   precompute(t+1): up-wait(cached), seq gather, stage+sync, a3 MFMA
// The a3 precompute sits in the publish->observe dead window (R5's win).
// No loads between epilogue and release sync (R6-R8 lesson: the vmcnt(0)
// drain before s_barrier puts any such load on the publish path).
// ---------------------------------------------------------------------------
__global__ __launch_bounds__(256, 1) void rnn_k(
    const float* __restrict__ hidden,
    const float* __restrict__ Wih0, const float* __restrict__ Whh0,
    const float* __restrict__ bih0, const float* __restrict__ bhh0,
    const float* __restrict__ WihL, const float* __restrict__ WhhL,
    const float* __restrict__ bihL, const float* __restrict__ bhhL,
    const unsigned short* __restrict__ xhi, const unsigned short* __restrict__ xlo,
    unsigned short* __restrict__ ring, unsigned short* __restrict__ seqr,
    unsigned short* __restrict__ s3, float* __restrict__ hn,
    unsigned* __restrict__ prog) {
  extern __shared__ char lds[];  // 64 KB: h 32K | seq 32K
  char* ldsH = lds;
  char* ldsS = lds + 32768;
  const int tid = threadIdx.x;
  const int wave = tid >> 6, lane = tid & 63;
  const int lm = lane & 15, lk = lane >> 4;
  const int bid = blockIdx.x;
  const int l = bid >> 6;
  const int sub = bid & 63;
  const int me = sub >> 2, bg = sub & 3;
  const int g = l * 4 + bg;
  const int j0 = me * 64 + wave * 16;
  const int j = j0 + lm;

  // ---- weight fragments (bf16-hi) in registers
  const float* Whh = (l == 0) ? Whh0 : WhhL + (size_t)(l - 1) * H_ * H_;
  bf16x8_t bh[32];
#pragma unroll
  for (int kit = 0; kit < 32; ++kit) {
    const float* src = Whh + (size_t)j * H_ + kit * 32 + lk * 8;
    union { bf16x8_t s; unsigned short u[8]; } th;
#pragma unroll
    for (int e = 0; e < 8; ++e) th.u[e] = (short)f2bf(src[e]);
    bh[kit] = th.s;
  }
  bf16x8_t bw[32];
  bf16x8_t w0h[4], w0l[4];
  if (l > 0) {
    const float* Wih = WihL + (size_t)(l - 1) * H_ * H_;
#pragma unroll
    for (int kit = 0; kit < 32; ++kit) {
      const float* src = Wih + (size_t)j * H_ + kit * 32 + lk * 8;
      union { bf16x8_t s; unsigned short u[8]; } th;
#pragma unroll
      for (int e = 0; e < 8; ++e) th.u[e] = (short)f2bf(src[e]);
      bw[kit] = th.s;
    }
  } else {
#pragma unroll
    for (int kit = 0; kit < 4; ++kit) {
      const float* src = Wih0 + (size_t)j * I_ + kit * 32 + lk * 8;
      union { bf16x8_t s; unsigned short u[8]; } th, tl;
#pragma unroll
      for (int e = 0; e < 8; ++e) {
        float v = src[e];
        unsigned short h = f2bf(v);
        th.u[e] = (short)h;
        tl.u[e] = (short)f2bf(v - bf2f(h));
      }
      w0h[kit] = th.s; w0l[kit] = tl.s;
    }
  }
  float bias = (l == 0) ? (bih0[j] + bhh0[j])
                        : (bihL[(size_t)(l - 1) * H_ + j] + bhhL[(size_t)(l - 1) * H_ + j]);

  // ---- init: h0 -> ring slot 1 (this block's 64-neuron portion, u32-packed)
  {
    unsigned* r1 = (unsigned*)(ring + ((size_t)(l * 2 + 1) * 4 + bg) * 16384);
#pragma unroll
    for (int q = 0; q < 2; ++q) {
      int s = q * 256 + tid;  // [0,512) -> u32 idx me*512 + s
      int J = s >> 6, b16 = (s >> 2) & 15, h4 = s & 3;
      int jj = me * 64 + J * 8 + h4 * 2;
      const float* hp = hidden + (size_t)l * B_ * H_ + (bg * 16 + b16) * H_ + jj;
      unsigned p0 = f2bf(hp[0]), p1 = f2bf(hp[1]);
      ast32(r1 + me * 512 + s, p0 | (p1 << 16));
    }
  }
  __syncthreads();  // drains vmcnt for the whole block
  if (tid == 0) ast32(prog + (size_t)(g * 16 + me) * 32, 1u);

  const unsigned* ownB = prog + (size_t)g * 512;
  const unsigned* upB = prog + (size_t)((l - 1) * 4 + bg) * 512;  // l>0 only
  const unsigned* dnB = prog + (size_t)((l + 1) * 4 + bg) * 512;  // l<3 only
  unsigned upMin = 1, dnMin = 1;
  f32x4_t a3s = {0.f, 0.f, 0.f, 0.f};
  unsigned long long htmp[16];
  unsigned long long stmp[16];

  // ---- input-projection precompute for step tt (fills a3s). R5 structure:
  // seq gather issued HERE (after publish), never before the release sync.
  // 4 independent MFMA accumulation chains (the R9 change).
  auto precompute = [&](int tt) {
    if (l > 0) {
      if (upMin < (unsigned)(tt + 2)) upMin = wait_ge(upB, (unsigned)(tt + 2));
      asm volatile("" ::: "memory");
      const unsigned long long* sp = (const unsigned long long*)(seqr +
          ((size_t)((l - 1) * D_ + (tt & (D_ - 1))) * 4 + bg) * 16384);
#pragma unroll
      for (int i = 0; i < 16; ++i) stmp[i] = ald64(sp + i * 256 + tid);
      unsigned long long* dsp = (unsigned long long*)ldsS;
#pragma unroll
      for (int i = 0; i < 16; ++i) dsp[i * 256 + tid] = stmp[i];
      __syncthreads();
      f32x4_t x0 = {0.f,0.f,0.f,0.f}, x1 = {0.f,0.f,0.f,0.f};
      f32x4_t x2 = {0.f,0.f,0.f,0.f}, x3 = {0.f,0.f,0.f,0.f};
#pragma unroll
      for (int kit = 0; kit < 32; ++kit) {
        const int fo = ((kit * 4 + lk) * 16 + lm) * 16;
        bf16x8_t as = *(const bf16x8_t*)(ldsS + fo);
        if ((kit & 3) == 0)      x0 = mfma16(as, bw[kit], x0);
        else if ((kit & 3) == 1) x1 = mfma16(as, bw[kit], x1);
        else if ((kit & 3) == 2) x2 = mfma16(as, bw[kit], x2);
        else                     x3 = mfma16(as, bw[kit], x3);
      }
      a3s = (x0 + x1) + (x2 + x3);
    } else {
      const int b = bg * 16 + lm;
      f32x4_t x0 = {0.f,0.f,0.f,0.f}, x1 = {0.f,0.f,0.f,0.f}, x2 = {0.f,0.f,0.f,0.f};
#pragma unroll
      for (int kit = 0; kit < 4; ++kit) {
        const size_t xo = ((size_t)b * T_ + tt) * I_ + kit * 32 + lk * 8;
        bf16x8_t xh = *(const bf16x8_t*)(xhi + xo);
        bf16x8_t xl = *(const bf16x8_t*)(xlo + xo);
        x0 = mfma16(xh, w0h[kit], x0);
        x1 = mfma16(xl, w0h[kit], x1);
        x2 = mfma16(xh, w0l[kit], x2);
      }
      a3s = (x0 + x1) + x2;
    }
  };

  precompute(0);

  for (int t = 0; t < T_; ++t) {
    // A. downstream back-pressure before overwriting seq slot (cached)
    if (l < 3 && t >= D_) {
      if (dnMin < (unsigned)(t - D_ + 2)) dnMin = wait_ge(dnB, (unsigned)(t - D_ + 2));
    }
    // B. own-group barrier: peers finished step t-1 (h_{t-1} visible)
    wait_all(ownB, (unsigned)(t + 1));
    asm volatile("" ::: "memory");
    // C. h slice gather (32 KB bf16-hi)
    const unsigned long long* hp = (const unsigned long long*)(ring +
        ((size_t)(l * 2 + ((t & 1) ^ 1)) * 4 + bg) * 16384);
#pragma unroll
    for (int i = 0; i < 16; ++i) htmp[i] = ald64(hp + i * 256 + tid);
    // D. stage h -> LDS (frag order preserved)
    {
      unsigned long long* dh = (unsigned long long*)ldsH;
#pragma unroll
      for (int i = 0; i < 16; ++i) dh[i * 256 + tid] = htmp[i];
    }
    __syncthreads();
    // E. a0 = h @ Whh^T (4 independent accumulation chains — R9 change)
    f32x4_t h0 = {0.f,0.f,0.f,0.f}, h1 = {0.f,0.f,0.f,0.f};
    f32x4_t h2 = {0.f,0.f,0.f,0.f}, h3 = {0.f,0.f,0.f,0.f};
#pragma unroll
    for (int kit = 0; kit < 32; ++kit) {
      const int fo = ((kit * 4 + lk) * 16 + lm) * 16;
      bf16x8_t ah = *(const bf16x8_t*)(ldsH + fo);
      if ((kit & 3) == 0)      h0 = mfma16(ah, bh[kit], h0);
      else if ((kit & 3) == 1) h1 = mfma16(ah, bh[kit], h1);
      else if ((kit & 3) == 2) h2 = mfma16(ah, bh[kit], h2);
      else                     h3 = mfma16(ah, bh[kit], h3);
    }
    f32x4_t a0 = (h0 + h1) + (h2 + h3);
    // F. epilogue: lane holds (j, b = bg*16 + lk*4 + r); u32 pair-packed stores
    unsigned* rwu = (unsigned*)(ring + ((size_t)(l * 2 + (t & 1)) * 4 + bg) * 16384);
    unsigned* swu = (unsigned*)(seqr + ((size_t)(l * D_ + (t & (D_ - 1))) * 4 + bg) * 16384);
#pragma unroll
    for (int r = 0; r < 4; ++r) {
      const int b15 = lk * 4 + r;
      float v = a0[r] + a3s[r] + bias;
      v = fmaxf(v, 0.f);
      unsigned hi = f2bf(v);
      unsigned other = (unsigned)__shfl_xor((int)hi, 1);
      if (!(lm & 1)) {
        const unsigned pk = hi | (other << 16);
        const int p32 = ((j >> 3) * 16 + b15) * 4 + ((j & 7) >> 1);
        ast32(rwu + p32, pk);
        if (l < 3) ast32(swu + p32, pk);
      }
      if (l == 3) s3[((size_t)(bg * 16 + b15) * T_ + t) * H_ + j] = (unsigned short)hi;
      if (t == T_ - 1) hn[(size_t)l * B_ * H_ + (bg * 16 + b15) * H_ + j] = v;
    }
    // G. release: __syncthreads drains all waves' stores, then publish.
    __syncthreads();
    if (tid == 0) ast32(prog + (size_t)(g * 16 + me) * 32, (unsigned)(t + 2));
    // H. precompute a3s for step t+1 inside the publish->observe window
    if (t + 1 < T_) precompute(t + 1);
  }
}

// ---------------------------------------------------------------------------
// ws layout: prog 32KB (16 groups x 16 members x 128B) | pad to 64K |
// ring 1MB (u16 [l][slot2][bg][16384]) | seqr 12MB | s3 64MB | xhi 8MB |
// xlo 8MB  => ~93 MB.
// ---------------------------------------------------------------------------
extern "C" void kernel_launch(void* const* d_in, const int* in_sizes, int n_in,
                              void* d_out, int out_size, void* d_ws, size_t ws_size,
                              hipStream_t stream) {
  const float* x = (const float*)d_in[0];
  const float* hidden = (const float*)d_in[1];
  const float* Wih0 = (const float*)d_in[2];
  const float* Whh0 = (const float*)d_in[3];
  const float* bih0 = (const float*)d_in[4];
  const float* bhh0 = (const float*)d_in[5];
  const float* WihL = (const float*)d_in[6];
  const float* WhhL = (const float*)d_in[7];
  const float* bihL = (const float*)d_in[8];
  const float* bhhL = (const float*)d_in[9];
  const float* Wfc = (const float*)d_in[10];
  const float* bfc = (const float*)d_in[11];
  float* out = (float*)d_out;
  float* hn = out + (size_t)M_ * O_;

  char* ws = (char*)d_ws;
  unsigned* prog = (unsigned*)ws;
  unsigned short* ring = (unsigned short*)(ws + 65536);
  unsigned short* seqr = (unsigned short*)(ws + 65536 + (1u << 20));
  unsigned short* s3 = (unsigned short*)(ws + 65536 + (1u << 20) + (12u << 20));
  unsigned short* xhi = (unsigned short*)(ws + 65536 + (1u << 20) + (12u << 20) + (64u << 20));
  unsigned short* xlo = xhi + (size_t)B_ * T_ * I_;

  hipMemsetAsync(ws, 0, 65536, stream);  // progress counters
  splitx_k<<<(B_ * T_ * I_) / 1024, 256, 0, stream>>>(x, xhi, xlo);

  hipFuncSetAttribute((const void*)rnn_k, hipFuncAttributeMaxDynamicSharedMemorySize,
                      64 * 1024);
  rnn_k<<<256, 256, 64 * 1024, stream>>>(hidden, Wih0, Whh0, bih0, bhh0,
                                         WihL, WhhL, bihL, bhhL, xhi, xlo,
                                         ring, seqr, s3, hn, prog);

  gemm_k<H_, O_, false, false><<<dim3(O_ / 128, M_ / 128), 256, 48 * 1024, stream>>>(
      (const void*)s3, Wfc, bfc, nullptr, (void*)out);
}